// Round 13
// baseline (217.780 us; speedup 1.0000x reference)
//
#include <hip/hip_runtime.h>
#include <stdint.h>

// MultiHeadAttention: x[4,2048,1024] fp32; Wq/Wk/Wv/Wo [1024,1024]; biases zero.
// out = softmax((xWq^T)(xWk^T)^T / 32) (xWv^T) Wo^T + bo   (16 heads, d=64)
//
// Pipeline (bf16 MFMA, fp32 accum):
//  k_cvt_all: x,W* fp32->bf16 (single fused launch)
//  k_gemm3: fused QKV projection, N=3072, XCD-partitioned grid.
//     V stored [bh][d][kv] with kv PRE-PERMUTED within each 16-token window
//     (groups {0,1,2,3}->{0,2,1,3}) so attn's PV B-frag is one contiguous
//     b128 LDS read matching the 32x32 MFMA k->kv map (proof: g2(2hi+(j>>2))
//     == 2(j>>2)+hi for all hi,j).
//  k_attn:  32x32x16 MFMA flash attention, fully in-register softmax,
//     ping-pong covered-drain staging. r12 failed with (__bf16) cast +
//     __builtin_amdgcn_exp2f; this round reverts BOTH to the r11-proven
//     forms (manual RNE f2bf, exp2f) keeping the permuted-V structure —
//     isolates the toolchain suspect from the layout change.
//  k_gemmo: O @ Wo^T + bo -> fp32 d_out, XCD-partitioned grid

#define HID 1024
#define NH 16
#define HD 64
#define BB 4
#define SEQ 2048
#define MTOT (BB * SEQ) // 8192

typedef short bf16x8 __attribute__((ext_vector_type(8)));
typedef float f32x4 __attribute__((ext_vector_type(4)));
typedef float f32x16 __attribute__((ext_vector_type(16)));

// swizzle: byte col within a 128B row, XORed by row&7 (16B granular)
#define SWZ(row, cb) ((cb) ^ (((row) & 7) << 4))

#define GLDS(gp, lp) __builtin_amdgcn_global_load_lds( \
    (const __attribute__((address_space(1))) void*)(gp), \
    (__attribute__((address_space(3))) void*)(lp), 16, 0, 0)

// f32 -> bf16 RNE, manual bit-twiddle (r11-proven; r12's (__bf16) cast failed)
static __device__ __forceinline__ unsigned short f2bf(float f) {
  unsigned u = __float_as_uint(f);
  u += 0x7fffu + ((u >> 16) & 1u); // RNE
  return (unsigned short)(u >> 16);
}

static __device__ __forceinline__ f32x4 mfma16(bf16x8 a, bf16x8 b, f32x4 c) {
  return __builtin_amdgcn_mfma_f32_16x16x32_bf16(a, b, c, 0, 0, 0);
}
static __device__ __forceinline__ f32x16 mfma32(bf16x8 a, bf16x8 b, f32x16 c) {
  return __builtin_amdgcn_mfma_f32_32x32x16_bf16(a, b, c, 0, 0, 0);
}

// ---------------- fp32 -> bf16 convert, all tensors, one launch ----------------
__global__ void k_cvt_all(const float* __restrict__ x,
                          const float* __restrict__ Wq, const float* __restrict__ Wk,
                          const float* __restrict__ Wv, const float* __restrict__ Wo,
                          unsigned short* __restrict__ ws) {
  const int X4 = MTOT * HID / 4;
  const int W4 = HID * HID / 4;
  int i = blockIdx.x * blockDim.x + threadIdx.x;
  const float* src;
  unsigned short* dst;
  int off;
  if (i < X4) {
    src = x; dst = ws; off = i;
  } else {
    int j = i - X4;
    int w = j / W4;
    off = j - w * W4;
    src = (w == 0) ? Wq : (w == 1) ? Wk : (w == 2) ? Wv : Wo;
    dst = ws + (size_t)MTOT * HID + (size_t)w * HID * HID;
  }
  float4 v = reinterpret_cast<const float4*>(src)[off];
  ushort4 o;
  o.x = f2bf(v.x); o.y = f2bf(v.y); o.z = f2bf(v.z); o.w = f2bf(v.w);
  reinterpret_cast<ushort4*>(dst)[off] = o;
}

// ---------------- fused QKV GEMM: [8192,3072] = A[M,K] @ W3[3N,K]^T ----------------
__global__ __launch_bounds__(256, 2) void k_gemm3(
    const unsigned short* __restrict__ A,
    const unsigned short* __restrict__ W3,
    const float* __restrict__ bq, const float* __restrict__ bk,
    const float* __restrict__ bv,
    unsigned short* __restrict__ Qo,   // [64][2048][64]
    unsigned short* __restrict__ Ko,   // [64][2048][64]
    unsigned short* __restrict__ Vto,  // [64][64][2048] kv-permuted per 16
    float cexp) {
  const int K = HID;
  __shared__ __align__(16) unsigned short sA[128 * 64];
  __shared__ __align__(16) unsigned short sB[128 * 64];
  const int orig = blockIdx.x + gridDim.x * blockIdx.y;
  const int xcd = orig & 7, idx = orig >> 3;
  const int gm = xcd & 3, gn = xcd >> 1 >> 1;
  const int m0 = (gm * 16 + (idx & 15)) * 128;
  const int n0 = (gn * 12 + (idx >> 4)) * 128;
  const int tid = threadIdx.x;
  const int lane = tid & 63, wid = tid >> 6;
  const int wr = wid >> 1, wc = wid & 1;
  const int lr = lane & 15, lg = lane >> 4;

  f32x4 acc[4][4] = {};

  const unsigned short* gA = A + (size_t)m0 * K;
  const unsigned short* gW = W3 + (size_t)n0 * K;

  for (int kt = 0; kt < K; kt += 64) {
#pragma unroll
    for (int i = 0; i < 4; ++i) {
      int c = tid + i * 256;
      int row = c >> 3, col = (c & 7) << 3;
      GLDS(gA + (size_t)row * K + kt + col, (char*)sA + (size_t)c * 16);
      GLDS(gW + (size_t)row * K + kt + col, (char*)sB + (size_t)c * 16);
    }
    __syncthreads();
#pragma unroll
    for (int kk = 0; kk < 64; kk += 32) {
      bf16x8 a[4], b[4];
      const int co = kk + lg * 8;
#pragma unroll
      for (int m = 0; m < 4; ++m)
        a[m] = *reinterpret_cast<const bf16x8*>(sA + (wr * 64 + m * 16 + lr) * 64 + co);
#pragma unroll
      for (int n = 0; n < 4; ++n)
        b[n] = *reinterpret_cast<const bf16x8*>(sB + (wc * 64 + n * 16 + lr) * 64 + co);
      __builtin_amdgcn_s_setprio(1);
#pragma unroll
      for (int m = 0; m < 4; ++m)
#pragma unroll
        for (int n = 0; n < 4; ++n)
          acc[m][n] = mfma16(a[m], b[n], acc[m][n]);
      __builtin_amdgcn_s_setprio(0);
    }
    __syncthreads();
  }

  const int sect = n0 >> 10; // 0=Q 1=K 2=V
  const float* bias = (sect == 0) ? bq : (sect == 1) ? bk : bv;
  const float sc = (sect == 0) ? cexp : 1.0f;

  if (sect < 2) {
    unsigned short* C = (sect == 0) ? Qo : Ko;
#pragma unroll
    for (int m = 0; m < 4; ++m) {
      int row0 = m0 + wr * 64 + m * 16 + lg * 4;
      int b = row0 >> 11;
#pragma unroll
      for (int n = 0; n < 4; ++n) {
        int colq = (n0 + wc * 64 + n * 16 + lr) & 1023;
        float bvv = bias[colq];
        int h = colq >> 6, d = colq & 63;
        size_t base = ((size_t)(b * NH + h) * SEQ) * HD + d;
#pragma unroll
        for (int r = 0; r < 4; ++r) {
          int tok = (row0 + r) & 2047;
          C[base + (size_t)tok * HD] = f2bf((acc[m][n][r] + bvv) * sc);
        }
      }
    }
  } else {
#pragma unroll
    for (int m = 0; m < 4; ++m) {
      int row0 = m0 + wr * 64 + m * 16 + lg * 4;
      int b = row0 >> 11;
      int tok0 = row0 & 2047;
      // kv-permute within each 16-window: 4-group g {0,1,2,3} -> {0,2,1,3}
      int g = (tok0 >> 2) & 3;
      int g2 = (g == 1) ? 2 : (g == 2) ? 1 : g;
      int tok_s = (tok0 & ~15) | (g2 << 2);
#pragma unroll
      for (int n = 0; n < 4; ++n) {
        int colq = (n0 + wc * 64 + n * 16 + lr) & 1023;
        float bvv = bias[colq];
        int h = colq >> 6, d = colq & 63;
        ushort4 pk;
        pk.x = f2bf(acc[m][n][0] + bvv);
        pk.y = f2bf(acc[m][n][1] + bvv);
        pk.z = f2bf(acc[m][n][2] + bvv);
        pk.w = f2bf(acc[m][n][3] + bvv);
        *reinterpret_cast<ushort4*>(&Vto[((size_t)(b * NH + h) * HD + d) * SEQ + tok_s]) = pk;
      }
    }
  }
}

// ---------------- out-proj GEMM: fp32 out = O @ Wo^T + bo ----------------
__global__ __launch_bounds__(256, 2) void k_gemmo(
    const unsigned short* __restrict__ A,
    const unsigned short* __restrict__ W,
    const float* __restrict__ bias,
    float* __restrict__ C) {
  const int K = HID;
  __shared__ __align__(16) unsigned short sA[128 * 64];
  __shared__ __align__(16) unsigned short sB[128 * 64];
  const int orig = blockIdx.x + gridDim.x * blockIdx.y;
  const int xcd = orig & 7, idx = orig >> 3;
  const int gm = xcd & 3, gn = xcd >> 2;
  const int m0 = (gm * 16 + (idx & 15)) * 128;
  const int n0 = (gn * 4 + (idx >> 4)) * 128;
  const int tid = threadIdx.x;
  const int lane = tid & 63, wid = tid >> 6;
  const int wr = wid >> 1, wc = wid & 1;
  const int lr = lane & 15, lg = lane >> 4;

  f32x4 acc[4][4] = {};

  const unsigned short* gA = A + (size_t)m0 * K;
  const unsigned short* gW = W + (size_t)n0 * K;

  for (int kt = 0; kt < K; kt += 64) {
#pragma unroll
    for (int i = 0; i < 4; ++i) {
      int c = tid + i * 256;
      int row = c >> 3, col = (c & 7) << 3;
      GLDS(gA + (size_t)row * K + kt + col, (char*)sA + (size_t)c * 16);
      GLDS(gW + (size_t)row * K + kt + col, (char*)sB + (size_t)c * 16);
    }
    __syncthreads();
#pragma unroll
    for (int kk = 0; kk < 64; kk += 32) {
      bf16x8 a[4], b[4];
      const int co = kk + lg * 8;
#pragma unroll
      for (int m = 0; m < 4; ++m)
        a[m] = *reinterpret_cast<const bf16x8*>(sA + (wr * 64 + m * 16 + lr) * 64 + co);
#pragma unroll
      for (int n = 0; n < 4; ++n)
        b[n] = *reinterpret_cast<const bf16x8*>(sB + (wc * 64 + n * 16 + lr) * 64 + co);
      __builtin_amdgcn_s_setprio(1);
#pragma unroll
      for (int m = 0; m < 4; ++m)
#pragma unroll
        for (int n = 0; n < 4; ++n)
          acc[m][n] = mfma16(a[m], b[n], acc[m][n]);
      __builtin_amdgcn_s_setprio(0);
    }
    __syncthreads();
  }

#pragma unroll
  for (int m = 0; m < 4; ++m) {
    int row0 = m0 + wr * 64 + m * 16 + lg * 4;
#pragma unroll
    for (int n = 0; n < 4; ++n) {
      int col = n0 + wc * 64 + n * 16 + lr;
      float bvv = bias[col];
#pragma unroll
      for (int r = 0; r < 4; ++r)
        C[(size_t)(row0 + r) * HID + col] = acc[m][n][r] + bvv;
    }
  }
}

// ---------------- attention: 32x32 MFMA, in-register softmax, ping-pong ----------------
// grid (bh=64, qt=16); 4 waves; wave owns 32 q-rows (band wid*32..+31).
// Per 64-kv tile (covered drains, 2 barriers, single 16KB buffer):
//   S (reads sK(t)) | B1 | stage K(t+1) | exp+pack (regs) ; PV (reads sV(t))
//   | B2 | stage V(t+1).
// S^T: lane(q=l31,hi): kv = nblk*32 + (reg&3)+8*(reg>>2)+4*hi.
// pa[i] = exp2f+f2bf in native order; V is kv-permuted in global so the PV
// B-frag is ONE b128 read (stored[8hi+j] == orig[(j&3)+8(j>>2)+4hi], proven).
#define KVB 64
#define NT (SEQ / KVB) // 32

__global__ __launch_bounds__(256, 4) void k_attn(
    const unsigned short* __restrict__ Qg,  // [64][2048][64]
    const unsigned short* __restrict__ Kg,  // [64][2048][64]
    const unsigned short* __restrict__ Vt,  // [64][64][2048] kv-permuted
    unsigned short* __restrict__ Og) {      // [8192][1024] bf16
  __shared__ __align__(16) unsigned short smem[128 * 64]; // 16KB

  const int bh = blockIdx.x;
  const int qt = blockIdx.y;
  const int tid = threadIdx.x;
  const int lane = tid & 63, wid = tid >> 6;
  const int l31 = lane & 31, hi = lane >> 5;

  const unsigned short* Kh = Kg + (size_t)bh * SEQ * HD;
  const unsigned short* Vh = Vt + (size_t)bh * HD * SEQ;

  char* sK = (char*)smem;           // [64 kv][128B]
  char* sV = (char*)smem + 8192;    // [64 d ][128B] (kv-permuted cols)

  // staging geometry: chunks c0=tid (row r0 in 0..31), c1=tid+256 (row r0+32)
  const int r0 = tid >> 3, r1 = r0 + 32;
  const int cb0 = SWZ(r0, (tid & 7) << 4) >> 1; // pre-swizzled source short-offset
  const int cb1 = SWZ(r1, (tid & 7) << 4) >> 1;

  // Q B-frags straight from global: row q = wid*32+l31, d = ks*16 + hi*8 + j
  bf16x8 qb[4];
  {
    const unsigned short* Qrow =
        Qg + ((size_t)bh * SEQ + (size_t)qt * 128 + wid * 32 + l31) * HD;
#pragma unroll
    for (int ks = 0; ks < 4; ++ks)
      qb[ks] = *reinterpret_cast<const bf16x8*>(Qrow + ks * 16 + hi * 8);
  }

  // prologue: stage K(0), V(0); one uncovered drain
  GLDS(Kh + (size_t)r0 * HD + cb0, sK + (size_t)tid * 16);
  GLDS(Kh + (size_t)r1 * HD + cb1, sK + (size_t)(tid + 256) * 16);
  GLDS(Vh + (size_t)r0 * SEQ + cb0, sV + (size_t)tid * 16);
  GLDS(Vh + (size_t)r1 * SEQ + cb1, sV + (size_t)(tid + 256) * 16);
  __syncthreads();

  const unsigned short onev = (unsigned short)0x3F80; // bf16 1.0
  const bf16x8 ones = {(short)onev, (short)onev, (short)onev, (short)onev,
                       (short)onev, (short)onev, (short)onev, (short)onev};

  f32x16 acco[2] = {};  // O: col d = dblk*32+l31, row q = crow(reg,hi)
  f32x16 accd = {};     // den, same layout

  for (int t = 0; t < NT; ++t) {
    const bool pf = (t + 1 < NT);
    const int ktn = (t + 1) * KVB;

    // S^T: accs[nblk], kv = nblk*32 + crow(reg,hi), q = l31
    f32x16 accs[2] = {};
#pragma unroll
    for (int ks = 0; ks < 4; ++ks) {
      bf16x8 ka0 = *reinterpret_cast<const bf16x8*>(
          sK + (0 + l31) * 128 + SWZ(l31, ks * 32 + hi * 16));
      bf16x8 ka1 = *reinterpret_cast<const bf16x8*>(
          sK + (32 + l31) * 128 + SWZ(32 + l31, ks * 32 + hi * 16));
      __builtin_amdgcn_s_setprio(1);
      accs[0] = mfma32(ka0, qb[ks], accs[0]);
      accs[1] = mfma32(ka1, qb[ks], accs[1]);
      __builtin_amdgcn_s_setprio(0);
    }

    __syncthreads(); // B1: all waves done with sK(t); drains V(t) (covered by S)
    if (pf) {        // stage K(t+1); drain at B2, covered by exp+PV
      GLDS(Kh + (size_t)(ktn + r0) * HD + cb0, sK + (size_t)tid * 16);
      GLDS(Kh + (size_t)(ktn + r1) * HD + cb1, sK + (size_t)(tid + 256) * 16);
    }

    // P = exp2(S^T) -> bf16 pa[i] in native lane order (scalar f2bf; the
    // compiler fuses adjacent pairs into v_cvt_pk_bf16_f32)
    bf16x8 pa[4];
#pragma unroll
    for (int nblk = 0; nblk < 2; ++nblk) {
#pragma unroll
      for (int g = 0; g < 2; ++g) {
        union { unsigned short s[8]; bf16x8 v; } u;
#pragma unroll
        for (int j = 0; j < 8; ++j)
          u.s[j] = f2bf(exp2f(accs[nblk][g * 8 + j]));
        pa[nblk * 2 + g] = u.v;
      }
    }

    // PV: O += P V ; den += P * ones. Instance i covers kv window i*16..+15;
    // V global layout is kv-permuted so the B-frag is one b128 read.
#pragma unroll
    for (int i = 0; i < 4; ++i) {
      bf16x8 vb[2];
#pragma unroll
      for (int dblk = 0; dblk < 2; ++dblk) {
        const int rsw = dblk * 32 + l31;
        vb[dblk] = *reinterpret_cast<const bf16x8*>(
            sV + rsw * 128 + SWZ(rsw, i * 32 + hi * 16));
      }
      __builtin_amdgcn_s_setprio(1);
      acco[0] = mfma32(pa[i], vb[0], acco[0]);
      acco[1] = mfma32(pa[i], vb[1], acco[1]);
      accd = mfma32(pa[i], ones, accd);
      __builtin_amdgcn_s_setprio(0);
    }

    __syncthreads(); // B2: all waves done with sV(t); drains K(t+1) (covered)
    if (pf) {        // stage V(t+1); drain at next B1, covered by S(t+1)
      GLDS(Vh + (size_t)r0 * SEQ + ktn + cb0, sV + (size_t)tid * 16);
      GLDS(Vh + (size_t)r1 * SEQ + ktn + cb1, sV + (size_t)(tid + 256) * 16);
    }
  }

  // epilogue: O[q][d] = acco/accd; q = crow(reg,hi), d = dblk*32 + l31
  const int b = bh >> 4, h = bh & 15;
#pragma unroll
  for (int reg = 0; reg < 16; ++reg) {
    int q = (reg & 3) + 8 * (reg >> 2) + 4 * hi;
    int tok = qt * 128 + wid * 32 + q;
    float rd = 1.0f / accd[reg];
    size_t rowoff = (size_t)(b * SEQ + tok) * HID + h * 64;
    Og[rowoff + l31] = f2bf(acco[0][reg] * rd);
    Og[rowoff + 32 + l31] = f2bf(acco[1][reg] * rd);
  }
}

// ---------------- launch ----------------
extern "C" void kernel_launch(void* const* d_in, const int* in_sizes, int n_in,
                              void* d_out, int out_size, void* d_ws, size_t ws_size,
                              hipStream_t stream) {
  (void)in_sizes; (void)n_in; (void)out_size; (void)ws_size;
  const float* x = (const float*)d_in[0];
  const float* Wq = (const float*)d_in[1];
  const float* bq = (const float*)d_in[2];
  const float* Wk = (const float*)d_in[3];
  const float* bk = (const float*)d_in[4];
  const float* Wv = (const float*)d_in[5];
  const float* bv = (const float*)d_in[6];
  const float* Wo = (const float*)d_in[7];
  const float* bo = (const float*)d_in[8];

  unsigned short* ws = (unsigned short*)d_ws;
  unsigned short* xb = ws;
  unsigned short* wqb = xb + (size_t)MTOT * HID;  // Wq;Wk;Wv;Wo contiguous
  unsigned short* wob = wqb + 3 * (size_t)HID * HID;
  unsigned short* qb = wob + (size_t)HID * HID;   // [64][2048][64]
  unsigned short* kb = qb + (size_t)MTOT * HID;   // [64][2048][64]
  unsigned short* vtb = kb + (size_t)MTOT * HID;  // [64][64][2048] kv-permuted
  unsigned short* ob = vtb + (size_t)MTOT * HID;  // [8192][1024]

  const float cexp = 0.04508422f; // log2(e)/32

  k_cvt_all<<<(MTOT * HID / 4 + 4 * (HID * HID / 4)) / 256, 256, 0, stream>>>(
      x, Wq, Wk, Wv, Wo, ws);

  k_gemm3<<<dim3(64, 24), 256, 0, stream>>>(
      xb, wqb, bq, bk, bv, qb, kb, vtb, cexp);

  k_attn<<<dim3(64, SEQ / 128), 256, 0, stream>>>(qb, kb, vtb, ob);

  k_gemmo<<<dim3(64, 8), 256, 0, stream>>>(ob, wob, bo, (float*)d_out);
}

// Round 16
// 208.664 us; speedup vs baseline: 1.0437x; 1.0437x over previous
//
#include <hip/hip_runtime.h>
#include <stdint.h>

// MultiHeadAttention: x[4,2048,1024] fp32; Wq/Wk/Wv/Wo [1024,1024]; biases zero.
// out = softmax((xWq^T)(xWk^T)^T / 32) (xWv^T) Wo^T + bo   (16 heads, d=64)
//
// Pipeline (bf16 MFMA, fp32 accum):
//  k_cvt_all: x,W* fp32->bf16 (single fused launch)
//  k_gemm3: fused QKV projection, N=3072, XCD-partitioned grid.
//     V stored [bh][d][kv], kv PRE-PERMUTED per 16-token window (groups
//     {0,1,2,3}->{0,2,1,3}) so attn's PV B-frag is one b128 LDS read.
//  k_attn: 32x32x16 MFMA flash attention, fully in-register softmax.
//     Staging = r10's PROVEN in-loop pattern: GLDS K,V -> barrier -> compute
//     -> barrier (deterministic; r15's covered-drain ping-pong raced under
//     schedule perturbation and never beat this anyway: 115.0 vs 113.7us).
//     exp = exp2f only (r14 asm v_exp hazard; r12 (__bf16)/builtin both bad).
//     pa packing = asm v_cvt_pk_bf16_f32 (proven in this structure at r10).
//  k_gemmo: O @ Wo^T + bo -> fp32 d_out, XCD-partitioned grid

#define HID 1024
#define NH 16
#define HD 64
#define BB 4
#define SEQ 2048
#define MTOT (BB * SEQ) // 8192

typedef short bf16x8 __attribute__((ext_vector_type(8)));
typedef float f32x4 __attribute__((ext_vector_type(4)));
typedef float f32x16 __attribute__((ext_vector_type(16)));

// swizzle: byte col within a 128B row, XORed by row&7 (16B granular)
#define SWZ(row, cb) ((cb) ^ (((row) & 7) << 4))

#define GLDS(gp, lp) __builtin_amdgcn_global_load_lds( \
    (const __attribute__((address_space(1))) void*)(gp), \
    (__attribute__((address_space(3))) void*)(lp), 16, 0, 0)

// f32 -> bf16 RNE, manual bit-twiddle (proven; (__bf16) cast failed in r12)
static __device__ __forceinline__ unsigned short f2bf(float f) {
  unsigned u = __float_as_uint(f);
  u += 0x7fffu + ((u >> 16) & 1u); // RNE
  return (unsigned short)(u >> 16);
}

static __device__ __forceinline__ f32x4 mfma16(bf16x8 a, bf16x8 b, f32x4 c) {
  return __builtin_amdgcn_mfma_f32_16x16x32_bf16(a, b, c, 0, 0, 0);
}
static __device__ __forceinline__ f32x16 mfma32(bf16x8 a, bf16x8 b, f32x16 c) {
  return __builtin_amdgcn_mfma_f32_32x32x16_bf16(a, b, c, 0, 0, 0);
}

// ---------------- fp32 -> bf16 convert, all tensors, one launch ----------------
__global__ void k_cvt_all(const float* __restrict__ x,
                          const float* __restrict__ Wq, const float* __restrict__ Wk,
                          const float* __restrict__ Wv, const float* __restrict__ Wo,
                          unsigned short* __restrict__ ws) {
  const int X4 = MTOT * HID / 4;
  const int W4 = HID * HID / 4;
  int i = blockIdx.x * blockDim.x + threadIdx.x;
  const float* src;
  unsigned short* dst;
  int off;
  if (i < X4) {
    src = x; dst = ws; off = i;
  } else {
    int j = i - X4;
    int w = j / W4;
    off = j - w * W4;
    src = (w == 0) ? Wq : (w == 1) ? Wk : (w == 2) ? Wv : Wo;
    dst = ws + (size_t)MTOT * HID + (size_t)w * HID * HID;
  }
  float4 v = reinterpret_cast<const float4*>(src)[off];
  ushort4 o;
  o.x = f2bf(v.x); o.y = f2bf(v.y); o.z = f2bf(v.z); o.w = f2bf(v.w);
  reinterpret_cast<ushort4*>(dst)[off] = o;
}

// ---------------- fused QKV GEMM: [8192,3072] = A[M,K] @ W3[3N,K]^T ----------------
__global__ __launch_bounds__(256, 2) void k_gemm3(
    const unsigned short* __restrict__ A,
    const unsigned short* __restrict__ W3,
    const float* __restrict__ bq, const float* __restrict__ bk,
    const float* __restrict__ bv,
    unsigned short* __restrict__ Qo,   // [64][2048][64]
    unsigned short* __restrict__ Ko,   // [64][2048][64]
    unsigned short* __restrict__ Vto,  // [64][64][2048] kv-permuted per 16
    float cexp) {
  const int K = HID;
  __shared__ __align__(16) unsigned short sA[128 * 64];
  __shared__ __align__(16) unsigned short sB[128 * 64];
  const int orig = blockIdx.x + gridDim.x * blockIdx.y;
  const int xcd = orig & 7, idx = orig >> 3;
  const int gm = xcd & 3, gn = xcd >> 1 >> 1;
  const int m0 = (gm * 16 + (idx & 15)) * 128;
  const int n0 = (gn * 12 + (idx >> 4)) * 128;
  const int tid = threadIdx.x;
  const int lane = tid & 63, wid = tid >> 6;
  const int wr = wid >> 1, wc = wid & 1;
  const int lr = lane & 15, lg = lane >> 4;

  f32x4 acc[4][4] = {};

  const unsigned short* gA = A + (size_t)m0 * K;
  const unsigned short* gW = W3 + (size_t)n0 * K;

  for (int kt = 0; kt < K; kt += 64) {
#pragma unroll
    for (int i = 0; i < 4; ++i) {
      int c = tid + i * 256;
      int row = c >> 3, col = (c & 7) << 3;
      GLDS(gA + (size_t)row * K + kt + col, (char*)sA + (size_t)c * 16);
      GLDS(gW + (size_t)row * K + kt + col, (char*)sB + (size_t)c * 16);
    }
    __syncthreads();
#pragma unroll
    for (int kk = 0; kk < 64; kk += 32) {
      bf16x8 a[4], b[4];
      const int co = kk + lg * 8;
#pragma unroll
      for (int m = 0; m < 4; ++m)
        a[m] = *reinterpret_cast<const bf16x8*>(sA + (wr * 64 + m * 16 + lr) * 64 + co);
#pragma unroll
      for (int n = 0; n < 4; ++n)
        b[n] = *reinterpret_cast<const bf16x8*>(sB + (wc * 64 + n * 16 + lr) * 64 + co);
      __builtin_amdgcn_s_setprio(1);
#pragma unroll
      for (int m = 0; m < 4; ++m)
#pragma unroll
        for (int n = 0; n < 4; ++n)
          acc[m][n] = mfma16(a[m], b[n], acc[m][n]);
      __builtin_amdgcn_s_setprio(0);
    }
    __syncthreads();
  }

  const int sect = n0 >> 10; // 0=Q 1=K 2=V
  const float* bias = (sect == 0) ? bq : (sect == 1) ? bk : bv;
  const float sc = (sect == 0) ? cexp : 1.0f;

  if (sect < 2) {
    unsigned short* C = (sect == 0) ? Qo : Ko;
#pragma unroll
    for (int m = 0; m < 4; ++m) {
      int row0 = m0 + wr * 64 + m * 16 + lg * 4;
      int b = row0 >> 11;
#pragma unroll
      for (int n = 0; n < 4; ++n) {
        int colq = (n0 + wc * 64 + n * 16 + lr) & 1023;
        float bvv = bias[colq];
        int h = colq >> 6, d = colq & 63;
        size_t base = ((size_t)(b * NH + h) * SEQ) * HD + d;
#pragma unroll
        for (int r = 0; r < 4; ++r) {
          int tok = (row0 + r) & 2047;
          C[base + (size_t)tok * HD] = f2bf((acc[m][n][r] + bvv) * sc);
        }
      }
    }
  } else {
#pragma unroll
    for (int m = 0; m < 4; ++m) {
      int row0 = m0 + wr * 64 + m * 16 + lg * 4;
      int b = row0 >> 11;
      int tok0 = row0 & 2047;
      // kv-permute within each 16-window: 4-group g {0,1,2,3} -> {0,2,1,3}
      int g = (tok0 >> 2) & 3;
      int g2 = (g == 1) ? 2 : (g == 2) ? 1 : g;
      int tok_s = (tok0 & ~15) | (g2 << 2);
#pragma unroll
      for (int n = 0; n < 4; ++n) {
        int colq = (n0 + wc * 64 + n * 16 + lr) & 1023;
        float bvv = bias[colq];
        int h = colq >> 6, d = colq & 63;
        ushort4 pk;
        pk.x = f2bf(acc[m][n][0] + bvv);
        pk.y = f2bf(acc[m][n][1] + bvv);
        pk.z = f2bf(acc[m][n][2] + bvv);
        pk.w = f2bf(acc[m][n][3] + bvv);
        *reinterpret_cast<ushort4*>(&Vto[((size_t)(b * NH + h) * HD + d) * SEQ + tok_s]) = pk;
      }
    }
  }
}

// ---------------- out-proj GEMM: fp32 out = O @ Wo^T + bo ----------------
__global__ __launch_bounds__(256, 2) void k_gemmo(
    const unsigned short* __restrict__ A,
    const unsigned short* __restrict__ W,
    const float* __restrict__ bias,
    float* __restrict__ C) {
  const int K = HID;
  __shared__ __align__(16) unsigned short sA[128 * 64];
  __shared__ __align__(16) unsigned short sB[128 * 64];
  const int orig = blockIdx.x + gridDim.x * blockIdx.y;
  const int xcd = orig & 7, idx = orig >> 3;
  const int gm = xcd & 3, gn = xcd >> 2;
  const int m0 = (gm * 16 + (idx & 15)) * 128;
  const int n0 = (gn * 4 + (idx >> 4)) * 128;
  const int tid = threadIdx.x;
  const int lane = tid & 63, wid = tid >> 6;
  const int wr = wid >> 1, wc = wid & 1;
  const int lr = lane & 15, lg = lane >> 4;

  f32x4 acc[4][4] = {};

  const unsigned short* gA = A + (size_t)m0 * K;
  const unsigned short* gW = W + (size_t)n0 * K;

  for (int kt = 0; kt < K; kt += 64) {
#pragma unroll
    for (int i = 0; i < 4; ++i) {
      int c = tid + i * 256;
      int row = c >> 3, col = (c & 7) << 3;
      GLDS(gA + (size_t)row * K + kt + col, (char*)sA + (size_t)c * 16);
      GLDS(gW + (size_t)row * K + kt + col, (char*)sB + (size_t)c * 16);
    }
    __syncthreads();
#pragma unroll
    for (int kk = 0; kk < 64; kk += 32) {
      bf16x8 a[4], b[4];
      const int co = kk + lg * 8;
#pragma unroll
      for (int m = 0; m < 4; ++m)
        a[m] = *reinterpret_cast<const bf16x8*>(sA + (wr * 64 + m * 16 + lr) * 64 + co);
#pragma unroll
      for (int n = 0; n < 4; ++n)
        b[n] = *reinterpret_cast<const bf16x8*>(sB + (wc * 64 + n * 16 + lr) * 64 + co);
      __builtin_amdgcn_s_setprio(1);
#pragma unroll
      for (int m = 0; m < 4; ++m)
#pragma unroll
        for (int n = 0; n < 4; ++n)
          acc[m][n] = mfma16(a[m], b[n], acc[m][n]);
      __builtin_amdgcn_s_setprio(0);
    }
    __syncthreads();
  }

#pragma unroll
  for (int m = 0; m < 4; ++m) {
    int row0 = m0 + wr * 64 + m * 16 + lg * 4;
#pragma unroll
    for (int n = 0; n < 4; ++n) {
      int col = n0 + wc * 64 + n * 16 + lr;
      float bvv = bias[col];
#pragma unroll
      for (int r = 0; r < 4; ++r)
        C[(size_t)(row0 + r) * HID + col] = acc[m][n][r] + bvv;
    }
  }
}

// ---------------- attention: 32x32 MFMA, in-register softmax ----------------
// grid (bh=64, qt=16); 4 waves; wave owns 32 q-rows (band wid*32..+31).
// Per 64-kv tile (r10-proven deterministic staging):
//   GLDS K(t),V(t) -> __syncthreads (drain) -> S -> exp/pack -> PV
//   -> __syncthreads (protect before next staging).
// S^T: lane(q=l31,hi): kv = nblk*32 + (reg&3)+8*(reg>>2)+4*hi.
// exp = exp2f; pa = asm cvt_pk pairs in native order; V kv-permuted in
// global so the PV B-frag is ONE b128 read. den via mfma(P, ones).
#define KVB 64

__global__ __launch_bounds__(256, 4) void k_attn(
    const unsigned short* __restrict__ Qg,  // [64][2048][64]
    const unsigned short* __restrict__ Kg,  // [64][2048][64]
    const unsigned short* __restrict__ Vt,  // [64][64][2048] kv-permuted
    unsigned short* __restrict__ Og) {      // [8192][1024] bf16
  __shared__ __align__(16) unsigned short smem[128 * 64]; // 16KB

  const int bh = blockIdx.x;
  const int qt = blockIdx.y;
  const int tid = threadIdx.x;
  const int lane = tid & 63, wid = tid >> 6;
  const int l31 = lane & 31, hi = lane >> 5;

  const unsigned short* Kh = Kg + (size_t)bh * SEQ * HD;
  const unsigned short* Vh = Vt + (size_t)bh * HD * SEQ;

  char* sK = (char*)smem;           // [64 kv][128B]
  char* sV = (char*)smem + 8192;    // [64 d ][128B] (kv-permuted cols)

  // staging geometry: chunks c0=tid (row r0 in 0..31), c1=tid+256 (row r0+32)
  const int r0 = tid >> 3, r1 = r0 + 32;
  const int cb0 = SWZ(r0, (tid & 7) << 4) >> 1; // pre-swizzled source short-offset
  const int cb1 = SWZ(r1, (tid & 7) << 4) >> 1;

  // Q B-frags straight from global: row q = wid*32+l31, d = ks*16 + hi*8 + j
  bf16x8 qb[4];
  {
    const unsigned short* Qrow =
        Qg + ((size_t)bh * SEQ + (size_t)qt * 128 + wid * 32 + l31) * HD;
#pragma unroll
    for (int ks = 0; ks < 4; ++ks)
      qb[ks] = *reinterpret_cast<const bf16x8*>(Qrow + ks * 16 + hi * 8);
  }

  const unsigned short onev = (unsigned short)0x3F80; // bf16 1.0
  const bf16x8 ones = {(short)onev, (short)onev, (short)onev, (short)onev,
                       (short)onev, (short)onev, (short)onev, (short)onev};

  f32x16 acco[2] = {};  // O: col d = dblk*32+l31, row q = crow(reg,hi)
  f32x16 accd = {};     // den, same layout

  for (int kt = 0; kt < SEQ; kt += KVB) {
    // stage K [64 kv][64 d] and V^T [64 d][64 kv] (pre-swizzled source)
    GLDS(Kh + (size_t)(kt + r0) * HD + cb0, sK + (size_t)tid * 16);
    GLDS(Kh + (size_t)(kt + r1) * HD + cb1, sK + (size_t)(tid + 256) * 16);
    GLDS(Vh + (size_t)r0 * SEQ + kt + cb0, sV + (size_t)tid * 16);
    GLDS(Vh + (size_t)r1 * SEQ + kt + cb1, sV + (size_t)(tid + 256) * 16);
    __syncthreads(); // staged tiles visible (vmcnt drained)

    // S^T: accs[nblk], kv = nblk*32 + crow(reg,hi), q = l31
    f32x16 accs[2] = {};
#pragma unroll
    for (int ks = 0; ks < 4; ++ks) {
      bf16x8 ka0 = *reinterpret_cast<const bf16x8*>(
          sK + (0 + l31) * 128 + SWZ(l31, ks * 32 + hi * 16));
      bf16x8 ka1 = *reinterpret_cast<const bf16x8*>(
          sK + (32 + l31) * 128 + SWZ(32 + l31, ks * 32 + hi * 16));
      __builtin_amdgcn_s_setprio(1);
      accs[0] = mfma32(ka0, qb[ks], accs[0]);
      accs[1] = mfma32(ka1, qb[ks], accs[1]);
      __builtin_amdgcn_s_setprio(0);
    }

    // P = exp2(S^T) via exp2f -> pa[i] via asm cvt_pk pairs (native order)
    bf16x8 pa[4];
#pragma unroll
    for (int nblk = 0; nblk < 2; ++nblk) {
      float p[16];
#pragma unroll
      for (int r = 0; r < 16; ++r) p[r] = exp2f(accs[nblk][r]);
#pragma unroll
      for (int g = 0; g < 2; ++g) {
        const int bs = g * 8;
        unsigned w0, w1, w2, w3;
        asm("v_cvt_pk_bf16_f32 %0, %1, %2" : "=v"(w0) : "v"(p[bs + 0]), "v"(p[bs + 1]));
        asm("v_cvt_pk_bf16_f32 %0, %1, %2" : "=v"(w1) : "v"(p[bs + 2]), "v"(p[bs + 3]));
        asm("v_cvt_pk_bf16_f32 %0, %1, %2" : "=v"(w2) : "v"(p[bs + 4]), "v"(p[bs + 5]));
        asm("v_cvt_pk_bf16_f32 %0, %1, %2" : "=v"(w3) : "v"(p[bs + 6]), "v"(p[bs + 7]));
        uint4 pk4; pk4.x = w0; pk4.y = w1; pk4.z = w2; pk4.w = w3;
        pa[nblk * 2 + g] = *reinterpret_cast<bf16x8*>(&pk4);
      }
    }

    // PV: O += P V ; den += P * ones. Instance i covers kv window i*16..+15;
    // V global layout is kv-permuted so the B-frag is one b128 read.
#pragma unroll
    for (int i = 0; i < 4; ++i) {
      bf16x8 vb[2];
#pragma unroll
      for (int dblk = 0; dblk < 2; ++dblk) {
        const int rsw = dblk * 32 + l31;
        vb[dblk] = *reinterpret_cast<const bf16x8*>(
            sV + rsw * 128 + SWZ(rsw, i * 32 + hi * 16));
      }
      __builtin_amdgcn_s_setprio(1);
      acco[0] = mfma32(pa[i], vb[0], acco[0]);
      acco[1] = mfma32(pa[i], vb[1], acco[1]);
      accd = mfma32(pa[i], ones, accd);
      __builtin_amdgcn_s_setprio(0);
    }

    __syncthreads(); // protect sK/sV before next tile's staging
  }

  // epilogue: O[q][d] = acco/accd; q = crow(reg,hi), d = dblk*32 + l31
  const int b = bh >> 4, h = bh & 15;
#pragma unroll
  for (int reg = 0; reg < 16; ++reg) {
    int q = (reg & 3) + 8 * (reg >> 2) + 4 * hi;
    int tok = qt * 128 + wid * 32 + q;
    float rd = 1.0f / accd[reg];
    size_t rowoff = (size_t)(b * SEQ + tok) * HID + h * 64;
    Og[rowoff + l31] = f2bf(acco[0][reg] * rd);
    Og[rowoff + 32 + l31] = f2bf(acco[1][reg] * rd);
  }
}

// ---------------- launch ----------------
extern "C" void kernel_launch(void* const* d_in, const int* in_sizes, int n_in,
                              void* d_out, int out_size, void* d_ws, size_t ws_size,
                              hipStream_t stream) {
  (void)in_sizes; (void)n_in; (void)out_size; (void)ws_size;
  const float* x = (const float*)d_in[0];
  const float* Wq = (const float*)d_in[1];
  const float* bq = (const float*)d_in[2];
  const float* Wk = (const float*)d_in[3];
  const float* bk = (const float*)d_in[4];
  const float* Wv = (const float*)d_in[5];
  const float* bv = (const float*)d_in[6];
  const float* Wo = (const float*)d_in[7];
  const float* bo = (const float*)d_in[8];

  unsigned short* ws = (unsigned short*)d_ws;
  unsigned short* xb = ws;
  unsigned short* wqb = xb + (size_t)MTOT * HID;  // Wq;Wk;Wv;Wo contiguous
  unsigned short* wob = wqb + 3 * (size_t)HID * HID;
  unsigned short* qb = wob + (size_t)HID * HID;   // [64][2048][64]
  unsigned short* kb = qb + (size_t)MTOT * HID;   // [64][2048][64]
  unsigned short* vtb = kb + (size_t)MTOT * HID;  // [64][64][2048] kv-permuted
  unsigned short* ob = vtb + (size_t)MTOT * HID;  // [8192][1024]

  const float cexp = 0.04508422f; // log2(e)/32

  k_cvt_all<<<(MTOT * HID / 4 + 4 * (HID * HID / 4)) / 256, 256, 0, stream>>>(
      x, Wq, Wk, Wv, Wo, ws);

  k_gemm3<<<dim3(64, 24), 256, 0, stream>>>(
      xb, wqb, bq, bk, bv, qb, kb, vtb, cexp);

  k_attn<<<dim3(64, SEQ / 128), 256, 0, stream>>>(qb, kb, vtb, ob);

  k_gemmo<<<dim3(64, 8), 256, 0, stream>>>(ob, wob, bo, (float*)d_out);
}

// Round 18
// 188.159 us; speedup vs baseline: 1.1574x; 1.1090x over previous
//
#include <hip/hip_runtime.h>
#include <stdint.h>

// MultiHeadAttention: x[4,2048,1024] fp32; Wq/Wk/Wv/Wo [1024,1024]; biases zero.
// out = softmax((xWq^T)(xWk^T)^T / 32) (xWv^T) Wo^T + bo   (16 heads, d=64)
//
// Pipeline (bf16 MFMA, fp32 accum):
//  k_cvt_all: x,W* fp32->bf16 (single fused launch)
//  k_gemm3: fused QKV projection, N=3072, XCD-partitioned grid.
//     V stored [bh][d][kv], kv PRE-PERMUTED per 16-token window (groups
//     {0,1,2,3}->{0,2,1,3}) so attn's PV B-frag is one b128 LDS read.
//     Q pre-scaled by log2(e)/32 (exp(x/32) == 2^(x*log2e/32)).
//  k_attn: 32x32x16 MFMA flash attention, fully in-register softmax.
//     Staging = r10/r16-proven in-loop pattern (deterministic).
//     exp+pack = ONE asm block: 16x v_exp_f32 then 8x v_cvt_pk_bf16_f32
//     with >=8-instruction TRANS->VALU spacing BY CONSTRUCTION. (r14/r17
//     failed because a lone v_exp feeding opaque asm cvt_pk sits inside the
//     TRANS wait-state window the hazard recognizer doesn't pad for asm;
//     exp2f passed only because its OCML tail ops provided the spacing.)
//  k_gemmo: O @ Wo^T + bo -> fp32 d_out, XCD-partitioned grid

#define HID 1024
#define NH 16
#define HD 64
#define BB 4
#define SEQ 2048
#define MTOT (BB * SEQ) // 8192

typedef short bf16x8 __attribute__((ext_vector_type(8)));
typedef float f32x4 __attribute__((ext_vector_type(4)));
typedef float f32x16 __attribute__((ext_vector_type(16)));

// swizzle: byte col within a 128B row, XORed by row&7 (16B granular)
#define SWZ(row, cb) ((cb) ^ (((row) & 7) << 4))

#define GLDS(gp, lp) __builtin_amdgcn_global_load_lds( \
    (const __attribute__((address_space(1))) void*)(gp), \
    (__attribute__((address_space(3))) void*)(lp), 16, 0, 0)

// f32 -> bf16 RNE, manual bit-twiddle (proven; (__bf16) cast failed in r12)
static __device__ __forceinline__ unsigned short f2bf(float f) {
  unsigned u = __float_as_uint(f);
  u += 0x7fffu + ((u >> 16) & 1u); // RNE
  return (unsigned short)(u >> 16);
}

static __device__ __forceinline__ f32x4 mfma16(bf16x8 a, bf16x8 b, f32x4 c) {
  return __builtin_amdgcn_mfma_f32_16x16x32_bf16(a, b, c, 0, 0, 0);
}
static __device__ __forceinline__ f32x16 mfma32(bf16x8 a, bf16x8 b, f32x16 c) {
  return __builtin_amdgcn_mfma_f32_32x32x16_bf16(a, b, c, 0, 0, 0);
}

// ---------------- fp32 -> bf16 convert, all tensors, one launch ----------------
__global__ void k_cvt_all(const float* __restrict__ x,
                          const float* __restrict__ Wq, const float* __restrict__ Wk,
                          const float* __restrict__ Wv, const float* __restrict__ Wo,
                          unsigned short* __restrict__ ws) {
  const int X4 = MTOT * HID / 4;
  const int W4 = HID * HID / 4;
  int i = blockIdx.x * blockDim.x + threadIdx.x;
  const float* src;
  unsigned short* dst;
  int off;
  if (i < X4) {
    src = x; dst = ws; off = i;
  } else {
    int j = i - X4;
    int w = j / W4;
    off = j - w * W4;
    src = (w == 0) ? Wq : (w == 1) ? Wk : (w == 2) ? Wv : Wo;
    dst = ws + (size_t)MTOT * HID + (size_t)w * HID * HID;
  }
  float4 v = reinterpret_cast<const float4*>(src)[off];
  ushort4 o;
  o.x = f2bf(v.x); o.y = f2bf(v.y); o.z = f2bf(v.z); o.w = f2bf(v.w);
  reinterpret_cast<ushort4*>(dst)[off] = o;
}

// ---------------- fused QKV GEMM: [8192,3072] = A[M,K] @ W3[3N,K]^T ----------------
__global__ __launch_bounds__(256, 2) void k_gemm3(
    const unsigned short* __restrict__ A,
    const unsigned short* __restrict__ W3,
    const float* __restrict__ bq, const float* __restrict__ bk,
    const float* __restrict__ bv,
    unsigned short* __restrict__ Qo,   // [64][2048][64]
    unsigned short* __restrict__ Ko,   // [64][2048][64]
    unsigned short* __restrict__ Vto,  // [64][64][2048] kv-permuted per 16
    float cexp) {
  const int K = HID;
  __shared__ __align__(16) unsigned short sA[128 * 64];
  __shared__ __align__(16) unsigned short sB[128 * 64];
  const int orig = blockIdx.x + gridDim.x * blockIdx.y;
  const int xcd = orig & 7, idx = orig >> 3;
  const int gm = xcd & 3, gn = xcd >> 1 >> 1;
  const int m0 = (gm * 16 + (idx & 15)) * 128;
  const int n0 = (gn * 12 + (idx >> 4)) * 128;
  const int tid = threadIdx.x;
  const int lane = tid & 63, wid = tid >> 6;
  const int wr = wid >> 1, wc = wid & 1;
  const int lr = lane & 15, lg = lane >> 4;

  f32x4 acc[4][4] = {};

  const unsigned short* gA = A + (size_t)m0 * K;
  const unsigned short* gW = W3 + (size_t)n0 * K;

  for (int kt = 0; kt < K; kt += 64) {
#pragma unroll
    for (int i = 0; i < 4; ++i) {
      int c = tid + i * 256;
      int row = c >> 3, col = (c & 7) << 3;
      GLDS(gA + (size_t)row * K + kt + col, (char*)sA + (size_t)c * 16);
      GLDS(gW + (size_t)row * K + kt + col, (char*)sB + (size_t)c * 16);
    }
    __syncthreads();
#pragma unroll
    for (int kk = 0; kk < 64; kk += 32) {
      bf16x8 a[4], b[4];
      const int co = kk + lg * 8;
#pragma unroll
      for (int m = 0; m < 4; ++m)
        a[m] = *reinterpret_cast<const bf16x8*>(sA + (wr * 64 + m * 16 + lr) * 64 + co);
#pragma unroll
      for (int n = 0; n < 4; ++n)
        b[n] = *reinterpret_cast<const bf16x8*>(sB + (wc * 64 + n * 16 + lr) * 64 + co);
      __builtin_amdgcn_s_setprio(1);
#pragma unroll
      for (int m = 0; m < 4; ++m)
#pragma unroll
        for (int n = 0; n < 4; ++n)
          acc[m][n] = mfma16(a[m], b[n], acc[m][n]);
      __builtin_amdgcn_s_setprio(0);
    }
    __syncthreads();
  }

  const int sect = n0 >> 10; // 0=Q 1=K 2=V
  const float* bias = (sect == 0) ? bq : (sect == 1) ? bk : bv;
  const float sc = (sect == 0) ? cexp : 1.0f;

  if (sect < 2) {
    unsigned short* C = (sect == 0) ? Qo : Ko;
#pragma unroll
    for (int m = 0; m < 4; ++m) {
      int row0 = m0 + wr * 64 + m * 16 + lg * 4;
      int b = row0 >> 11;
#pragma unroll
      for (int n = 0; n < 4; ++n) {
        int colq = (n0 + wc * 64 + n * 16 + lr) & 1023;
        float bvv = bias[colq];
        int h = colq >> 6, d = colq & 63;
        size_t base = ((size_t)(b * NH + h) * SEQ) * HD + d;
#pragma unroll
        for (int r = 0; r < 4; ++r) {
          int tok = (row0 + r) & 2047;
          C[base + (size_t)tok * HD] = f2bf((acc[m][n][r] + bvv) * sc);
        }
      }
    }
  } else {
#pragma unroll
    for (int m = 0; m < 4; ++m) {
      int row0 = m0 + wr * 64 + m * 16 + lg * 4;
      int b = row0 >> 11;
      int tok0 = row0 & 2047;
      // kv-permute within each 16-window: 4-group g {0,1,2,3} -> {0,2,1,3}
      int g = (tok0 >> 2) & 3;
      int g2 = (g == 1) ? 2 : (g == 2) ? 1 : g;
      int tok_s = (tok0 & ~15) | (g2 << 2);
#pragma unroll
      for (int n = 0; n < 4; ++n) {
        int colq = (n0 + wc * 64 + n * 16 + lr) & 1023;
        float bvv = bias[colq];
        int h = colq >> 6, d = colq & 63;
        ushort4 pk;
        pk.x = f2bf(acc[m][n][0] + bvv);
        pk.y = f2bf(acc[m][n][1] + bvv);
        pk.z = f2bf(acc[m][n][2] + bvv);
        pk.w = f2bf(acc[m][n][3] + bvv);
        *reinterpret_cast<ushort4*>(&Vto[((size_t)(b * NH + h) * HD + d) * SEQ + tok_s]) = pk;
      }
    }
  }
}

// ---------------- out-proj GEMM: fp32 out = O @ Wo^T + bo ----------------
__global__ __launch_bounds__(256, 2) void k_gemmo(
    const unsigned short* __restrict__ A,
    const unsigned short* __restrict__ W,
    const float* __restrict__ bias,
    float* __restrict__ C) {
  const int K = HID;
  __shared__ __align__(16) unsigned short sA[128 * 64];
  __shared__ __align__(16) unsigned short sB[128 * 64];
  const int orig = blockIdx.x + gridDim.x * blockIdx.y;
  const int xcd = orig & 7, idx = orig >> 3;
  const int gm = xcd & 3, gn = xcd >> 2;
  const int m0 = (gm * 16 + (idx & 15)) * 128;
  const int n0 = (gn * 4 + (idx >> 4)) * 128;
  const int tid = threadIdx.x;
  const int lane = tid & 63, wid = tid >> 6;
  const int wr = wid >> 1, wc = wid & 1;
  const int lr = lane & 15, lg = lane >> 4;

  f32x4 acc[4][4] = {};

  const unsigned short* gA = A + (size_t)m0 * K;
  const unsigned short* gW = W + (size_t)n0 * K;

  for (int kt = 0; kt < K; kt += 64) {
#pragma unroll
    for (int i = 0; i < 4; ++i) {
      int c = tid + i * 256;
      int row = c >> 3, col = (c & 7) << 3;
      GLDS(gA + (size_t)row * K + kt + col, (char*)sA + (size_t)c * 16);
      GLDS(gW + (size_t)row * K + kt + col, (char*)sB + (size_t)c * 16);
    }
    __syncthreads();
#pragma unroll
    for (int kk = 0; kk < 64; kk += 32) {
      bf16x8 a[4], b[4];
      const int co = kk + lg * 8;
#pragma unroll
      for (int m = 0; m < 4; ++m)
        a[m] = *reinterpret_cast<const bf16x8*>(sA + (wr * 64 + m * 16 + lr) * 64 + co);
#pragma unroll
      for (int n = 0; n < 4; ++n)
        b[n] = *reinterpret_cast<const bf16x8*>(sB + (wc * 64 + n * 16 + lr) * 64 + co);
      __builtin_amdgcn_s_setprio(1);
#pragma unroll
      for (int m = 0; m < 4; ++m)
#pragma unroll
        for (int n = 0; n < 4; ++n)
          acc[m][n] = mfma16(a[m], b[n], acc[m][n]);
      __builtin_amdgcn_s_setprio(0);
    }
    __syncthreads();
  }

#pragma unroll
  for (int m = 0; m < 4; ++m) {
    int row0 = m0 + wr * 64 + m * 16 + lg * 4;
#pragma unroll
    for (int n = 0; n < 4; ++n) {
      int col = n0 + wc * 64 + n * 16 + lr;
      float bvv = bias[col];
#pragma unroll
      for (int r = 0; r < 4; ++r)
        C[(size_t)(row0 + r) * HID + col] = acc[m][n][r] + bvv;
    }
  }
}

// ---------------- attention: 32x32 MFMA, in-register softmax ----------------
// grid (bh=64, qt=16); 4 waves; wave owns 32 q-rows (band wid*32..+31).
// Per 64-kv tile (r10/r16-proven deterministic staging):
//   GLDS K(t),V(t) -> __syncthreads (drain) -> S -> exp/pack -> PV
//   -> __syncthreads (protect before next staging).
// S^T: lane(q=l31,hi): kv = nblk*32 + (reg&3)+8*(reg>>2)+4*hi.
// exp+pack: single asm block (16 v_exp then s_nop then 8 cvt_pk) — TRANS
// hazard spacing by construction. V kv-permuted -> PV B-frag one b128 read.
// den via mfma(P, ones).
#define KVB 64

__global__ __launch_bounds__(256, 4) void k_attn(
    const unsigned short* __restrict__ Qg,  // [64][2048][64]
    const unsigned short* __restrict__ Kg,  // [64][2048][64]
    const unsigned short* __restrict__ Vt,  // [64][64][2048] kv-permuted
    unsigned short* __restrict__ Og) {      // [8192][1024] bf16
  __shared__ __align__(16) unsigned short smem[128 * 64]; // 16KB

  const int bh = blockIdx.x;
  const int qt = blockIdx.y;
  const int tid = threadIdx.x;
  const int lane = tid & 63, wid = tid >> 6;
  const int l31 = lane & 31, hi = lane >> 5;

  const unsigned short* Kh = Kg + (size_t)bh * SEQ * HD;
  const unsigned short* Vh = Vt + (size_t)bh * HD * SEQ;

  char* sK = (char*)smem;           // [64 kv][128B]
  char* sV = (char*)smem + 8192;    // [64 d ][128B] (kv-permuted cols)

  // staging geometry: chunks c0=tid (row r0 in 0..31), c1=tid+256 (row r0+32)
  const int r0 = tid >> 3, r1 = r0 + 32;
  const int cb0 = SWZ(r0, (tid & 7) << 4) >> 1; // pre-swizzled source short-offset
  const int cb1 = SWZ(r1, (tid & 7) << 4) >> 1;

  // Q B-frags straight from global: row q = wid*32+l31, d = ks*16 + hi*8 + j
  bf16x8 qb[4];
  {
    const unsigned short* Qrow =
        Qg + ((size_t)bh * SEQ + (size_t)qt * 128 + wid * 32 + l31) * HD;
#pragma unroll
    for (int ks = 0; ks < 4; ++ks)
      qb[ks] = *reinterpret_cast<const bf16x8*>(Qrow + ks * 16 + hi * 8);
  }

  const unsigned short onev = (unsigned short)0x3F80; // bf16 1.0
  const bf16x8 ones = {(short)onev, (short)onev, (short)onev, (short)onev,
                       (short)onev, (short)onev, (short)onev, (short)onev};

  f32x16 acco[2] = {};  // O: col d = dblk*32+l31, row q = crow(reg,hi)
  f32x16 accd = {};     // den, same layout

  for (int kt = 0; kt < SEQ; kt += KVB) {
    // stage K [64 kv][64 d] and V^T [64 d][64 kv] (pre-swizzled source)
    GLDS(Kh + (size_t)(kt + r0) * HD + cb0, sK + (size_t)tid * 16);
    GLDS(Kh + (size_t)(kt + r1) * HD + cb1, sK + (size_t)(tid + 256) * 16);
    GLDS(Vh + (size_t)r0 * SEQ + kt + cb0, sV + (size_t)tid * 16);
    GLDS(Vh + (size_t)r1 * SEQ + kt + cb1, sV + (size_t)(tid + 256) * 16);
    __syncthreads(); // staged tiles visible (vmcnt drained)

    // S^T: accs[nblk], kv = nblk*32 + crow(reg,hi), q = l31
    f32x16 accs[2] = {};
#pragma unroll
    for (int ks = 0; ks < 4; ++ks) {
      bf16x8 ka0 = *reinterpret_cast<const bf16x8*>(
          sK + (0 + l31) * 128 + SWZ(l31, ks * 32 + hi * 16));
      bf16x8 ka1 = *reinterpret_cast<const bf16x8*>(
          sK + (32 + l31) * 128 + SWZ(32 + l31, ks * 32 + hi * 16));
      __builtin_amdgcn_s_setprio(1);
      accs[0] = mfma32(ka0, qb[ks], accs[0]);
      accs[1] = mfma32(ka1, qb[ks], accs[1]);
      __builtin_amdgcn_s_setprio(0);
    }

    // P = 2^(S*log2e/32): ONE asm block per 16 values — 16 v_exp then 8
    // cvt_pk, >=8-instr TRANS->VALU spacing by construction.
    bf16x8 pa[4];
#pragma unroll
    for (int nblk = 0; nblk < 2; ++nblk) {
      float p0 = accs[nblk][0],  p1 = accs[nblk][1],  p2 = accs[nblk][2],  p3 = accs[nblk][3];
      float p4 = accs[nblk][4],  p5 = accs[nblk][5],  p6 = accs[nblk][6],  p7 = accs[nblk][7];
      float p8 = accs[nblk][8],  p9 = accs[nblk][9],  p10 = accs[nblk][10], p11 = accs[nblk][11];
      float p12 = accs[nblk][12], p13 = accs[nblk][13], p14 = accs[nblk][14], p15 = accs[nblk][15];
      unsigned w0, w1, w2, w3, w4, w5, w6, w7;
      asm("v_exp_f32 %8, %8\n\t"
          "v_exp_f32 %9, %9\n\t"
          "v_exp_f32 %10, %10\n\t"
          "v_exp_f32 %11, %11\n\t"
          "v_exp_f32 %12, %12\n\t"
          "v_exp_f32 %13, %13\n\t"
          "v_exp_f32 %14, %14\n\t"
          "v_exp_f32 %15, %15\n\t"
          "v_exp_f32 %16, %16\n\t"
          "v_exp_f32 %17, %17\n\t"
          "v_exp_f32 %18, %18\n\t"
          "v_exp_f32 %19, %19\n\t"
          "v_exp_f32 %20, %20\n\t"
          "v_exp_f32 %21, %21\n\t"
          "v_exp_f32 %22, %22\n\t"
          "v_exp_f32 %23, %23\n\t"
          "s_nop 3\n\t"
          "v_cvt_pk_bf16_f32 %0, %8, %9\n\t"
          "v_cvt_pk_bf16_f32 %1, %10, %11\n\t"
          "v_cvt_pk_bf16_f32 %2, %12, %13\n\t"
          "v_cvt_pk_bf16_f32 %3, %14, %15\n\t"
          "v_cvt_pk_bf16_f32 %4, %16, %17\n\t"
          "v_cvt_pk_bf16_f32 %5, %18, %19\n\t"
          "v_cvt_pk_bf16_f32 %6, %20, %21\n\t"
          "v_cvt_pk_bf16_f32 %7, %22, %23"
          : "=&v"(w0), "=&v"(w1), "=&v"(w2), "=&v"(w3),
            "=&v"(w4), "=&v"(w5), "=&v"(w6), "=&v"(w7),
            "+v"(p0), "+v"(p1), "+v"(p2), "+v"(p3),
            "+v"(p4), "+v"(p5), "+v"(p6), "+v"(p7),
            "+v"(p8), "+v"(p9), "+v"(p10), "+v"(p11),
            "+v"(p12), "+v"(p13), "+v"(p14), "+v"(p15));
      uint4 lo4; lo4.x = w0; lo4.y = w1; lo4.z = w2; lo4.w = w3;
      uint4 hi4; hi4.x = w4; hi4.y = w5; hi4.z = w6; hi4.w = w7;
      pa[nblk * 2 + 0] = *reinterpret_cast<bf16x8*>(&lo4);
      pa[nblk * 2 + 1] = *reinterpret_cast<bf16x8*>(&hi4);
    }

    // PV: O += P V ; den += P * ones. Instance i covers kv window i*16..+15;
    // V global layout is kv-permuted so the B-frag is one b128 read.
#pragma unroll
    for (int i = 0; i < 4; ++i) {
      bf16x8 vb[2];
#pragma unroll
      for (int dblk = 0; dblk < 2; ++dblk) {
        const int rsw = dblk * 32 + l31;
        vb[dblk] = *reinterpret_cast<const bf16x8*>(
            sV + rsw * 128 + SWZ(rsw, i * 32 + hi * 16));
      }
      __builtin_amdgcn_s_setprio(1);
      acco[0] = mfma32(pa[i], vb[0], acco[0]);
      acco[1] = mfma32(pa[i], vb[1], acco[1]);
      accd = mfma32(pa[i], ones, accd);
      __builtin_amdgcn_s_setprio(0);
    }

    __syncthreads(); // protect sK/sV before next tile's staging
  }

  // epilogue: O[q][d] = acco/accd; q = crow(reg,hi), d = dblk*32 + l31
  const int b = bh >> 4, h = bh & 15;
#pragma unroll
  for (int reg = 0; reg < 16; ++reg) {
    int q = (reg & 3) + 8 * (reg >> 2) + 4 * hi;
    int tok = qt * 128 + wid * 32 + q;
    float rd = 1.0f / accd[reg];
    size_t rowoff = (size_t)(b * SEQ + tok) * HID + h * 64;
    Og[rowoff + l31] = f2bf(acco[0][reg] * rd);
    Og[rowoff + 32 + l31] = f2bf(acco[1][reg] * rd);
  }
}

// ---------------- launch ----------------
extern "C" void kernel_launch(void* const* d_in, const int* in_sizes, int n_in,
                              void* d_out, int out_size, void* d_ws, size_t ws_size,
                              hipStream_t stream) {
  (void)in_sizes; (void)n_in; (void)out_size; (void)ws_size;
  const float* x = (const float*)d_in[0];
  const float* Wq = (const float*)d_in[1];
  const float* bq = (const float*)d_in[2];
  const float* Wk = (const float*)d_in[3];
  const float* bk = (const float*)d_in[4];
  const float* Wv = (const float*)d_in[5];
  const float* bv = (const float*)d_in[6];
  const float* Wo = (const float*)d_in[7];
  const float* bo = (const float*)d_in[8];

  unsigned short* ws = (unsigned short*)d_ws;
  unsigned short* xb = ws;
  unsigned short* wqb = xb + (size_t)MTOT * HID;  // Wq;Wk;Wv;Wo contiguous
  unsigned short* wob = wqb + 3 * (size_t)HID * HID;
  unsigned short* qb = wob + (size_t)HID * HID;   // [64][2048][64]
  unsigned short* kb = qb + (size_t)MTOT * HID;   // [64][2048][64]
  unsigned short* vtb = kb + (size_t)MTOT * HID;  // [64][64][2048] kv-permuted
  unsigned short* ob = vtb + (size_t)MTOT * HID;  // [8192][1024]

  const float cexp = 0.04508422f; // log2(e)/32 — attn computes 2^(S*cexp)

  k_cvt_all<<<(MTOT * HID / 4 + 4 * (HID * HID / 4)) / 256, 256, 0, stream>>>(
      x, Wq, Wk, Wv, Wo, ws);

  k_gemm3<<<dim3(64, 24), 256, 0, stream>>>(
      xb, wqb, bq, bk, bv, qb, kb, vtb, cexp);

  k_attn<<<dim3(64, SEQ / 128), 256, 0, stream>>>(qb, kb, vtb, ob);

  k_gemmo<<<dim3(64, 8), 256, 0, stream>>>(ob, wob, bo, (float*)d_out);
}